// Round 16
// baseline (55.044 us; speedup 1.0000x reference)
//
#include <hip/hip_runtime.h>
#include <hip/hip_bf16.h>

#define POOLED 7
#define PP 49
#define SCALE 0.0625f
#define RMAX 20   // max rows per p-bin: bh<=14.2 -> tight support <= 17
#define QMAX 32   // max cols per q-bin + 4-step unroll padding; zero-filled
#define TW 256    // 4 waves = 4 row-slots

// antiderivative of unit hat: Phi(u), Phi(-inf)=0, matches reference _hat_cdf
__device__ __forceinline__ float hat_cdf(float u) {
  if (u <= 0.0f) {
    float t = fminf(fmaxf(u + 1.0f, 0.0f), 1.0f);
    return 0.5f * t * t;
  } else {
    float t = fminf(fmaxf(1.0f - u, 0.0f), 1.0f);
    return 1.0f - 0.5f * t * t;
  }
}

__device__ __forceinline__ float bf_lo(uint32_t u) { return __uint_as_float(u << 16); }
__device__ __forceinline__ float bf_hi(uint32_t u) { return __uint_as_float(u & 0xffff0000u); }

// A[8] += unpack8(U) * WT  (params must not collide with .x/.y/.z/.w members)
#define FMA8(A, U, WT) do { \
  (A)[0] = fmaf(bf_lo((U).x), (WT), (A)[0]); (A)[1] = fmaf(bf_hi((U).x), (WT), (A)[1]); \
  (A)[2] = fmaf(bf_lo((U).y), (WT), (A)[2]); (A)[3] = fmaf(bf_hi((U).y), (WT), (A)[3]); \
  (A)[4] = fmaf(bf_lo((U).z), (WT), (A)[4]); (A)[5] = fmaf(bf_hi((U).z), (WT), (A)[5]); \
  (A)[6] = fmaf(bf_lo((U).w), (WT), (A)[6]); (A)[7] = fmaf(bf_hi((U).w), (WT), (A)[7]); \
} while (0)

// f32 [B][C][S] -> bf16 [B][S][C]  (S = H*W), coalesced both sides
__global__ __launch_bounds__(256)
void transpose_bf16_kernel(const float* __restrict__ in,
                           __hip_bfloat16* __restrict__ out, int C, int S) {
  __shared__ float tile[32][33];
  int b  = blockIdx.z;
  int s0 = blockIdx.x * 32;
  int c0 = blockIdx.y * 32;
  const float* inb = in + (size_t)b * C * S;
  __hip_bfloat16* outb = out + (size_t)b * S * C;
  int tx = threadIdx.x, ty = threadIdx.y;
#pragma unroll
  for (int j = 0; j < 4; j++) {
    int c = c0 + ty + j * 8, s = s0 + tx;
    tile[ty + j * 8][tx] = (c < C && s < S) ? inb[(size_t)c * S + s] : 0.0f;
  }
  __syncthreads();
#pragma unroll
  for (int j = 0; j < 4; j++) {
    int s = s0 + ty + j * 8, c = c0 + tx;
    if (s < S && c < C) outb[(size_t)s * C + c] = __float2bfloat16(tile[tx][ty + j * 8]);
  }
}

// One 4-wave block per (roi n, bin p, bin q) -- r15 structure (finest granule,
// 12544 blocks, chunked XCD swizzle, bf16 NHWC scratch, uint4 half-wave loads:
// lane l owns 8 ch ((l&31)*8), bit l>>5 picks cell parity). r16 changes:
// (1) 4-sub-step unrolled inner loop -> 8 uint4 loads in flight per body
//     (uniform padded trip: clamped addresses + zero-padded s_wx, so over-
//     read cells hit L1 with exactly-zero weight);
// (2) no weight barrier: each wave redundantly computes ALL weights (<=1
//     hat_cdf pair per lane) and writes identical values; within-wave
//     lgkmcnt ordering makes its own reads safe -> one barrier per block.
__global__ __launch_bounds__(TW, 4)
void prroi_kernel(const __hip_bfloat16* __restrict__ ft,
                  const float* __restrict__ rois,
                  float* __restrict__ out, int N, int C, int H, int W) {
  __shared__ float s_wx[QMAX];
  __shared__ float s_wy[RMAX];
  __shared__ float s_red[4 * 32 * 9];  // 4,608 B; stride 9 coprime w/ 32 banks

  int nb = gridDim.x;
  int bid = blockIdx.x;
  if ((nb & 7) == 0) {
    // chunked XCD swizzle: one ROI's 49 blocks stay on one XCD for L2 reuse
    int cpx = nb >> 3;
    bid = (bid & 7) * cpx + (bid >> 3);
  }
  int n = bid / PP;
  int pq = bid - n * PP;
  int p = pq / POOLED, q = pq - p * POOLED;

  int tid = threadIdx.x;
  int wave = tid >> 6, lane = tid & 63;  // wave = row-slot
  int l5 = lane >> 5;                    // cell parity this lane covers
  int l31 = lane & 31;                   // channel-octet index (8 ch)

  // uniform roi geometry (broadcast loads)
  float bif = rois[n * 5 + 0];
  float x1  = rois[n * 5 + 1] * SCALE;
  float y1  = rois[n * 5 + 2] * SCALE;
  float x2  = rois[n * 5 + 3] * SCALE;
  float y2  = rois[n * 5 + 4] * SCALE;
  int bi = (int)bif;
  float bw = (x2 - x1) * (1.0f / POOLED);
  float bh = (y2 - y1) * (1.0f / POOLED);
  float ylo = y1 + p * bh, yhi = ylo + bh;
  float xlo = x1 + q * bw, xhi = xlo + bw;

  // tight supports (next cell out has exactly-zero hat weight)
  int h0 = max(0, (int)floorf(ylo));
  int h1 = min(H - 1, (int)ceilf(yhi));
  int rows = h1 - h0 + 1;
  if (rows > RMAX) rows = RMAX;      // cannot trigger here; safety only
  int w0 = max(0, (int)floorf(xlo));
  int w1 = min(W - 1, (int)ceilf(xhi));
  int nw = w1 - w0 + 1;
  if (nw > QMAX - 8) nw = QMAX - 8;  // cannot trigger here; safety only

  float area = fmaxf(bw * bh, 0.0f);
  float inv_area = (area > 0.0f) ? 1.0f / fmaxf(area, 1e-12f) : 0.0f;

  // per-wave redundant weight fill (identical values from every wave -> no
  // cross-wave barrier; within-wave lgkmcnt orders write->read). QMAX=32 and
  // rows<=20 both < 64, so one lane-pass per wave covers everything.
  {
    int i = lane;
    if (i < QMAX) {
      float v = 0.0f;
      if (i < nw) {
        float j = (float)(w0 + i);
        v = (hat_cdf(xhi - j) - hat_cdf(xlo - j)) * inv_area;
      }
      s_wx[i] = v;
    }
    if (i < rows) {
      float j = (float)(h0 + i);
      s_wy[i] = hat_cdf(yhi - j) - hat_cdf(ylo - j);
    }
  }

  float acc[8];
#pragma unroll
  for (int k = 0; k < 8; k++) acc[k] = 0.0f;

  const int C8 = C >> 3;  // uint4 (=8ch) per cell
  const uint4* lp = (const uint4*)ft + ((size_t)bi * H * W) * C8 + l31;
  const int ns = (nw + 1) >> 1;  // cell-pair steps (block-uniform)
  const int cmax = nw - 1;       // address clamp (weight exactly 0 beyond)

  // rows round-robin over 4 row-slots; fuse pairs (ih, ih+4); 4-step unroll
  for (int ih = wave; ih < rows; ih += 8) {
    int iA = ih, iB = ih + 4;
    float wyA = s_wy[iA];
    float wyB = (iB < rows) ? s_wy[iB] : 0.0f;
    if (wyA == 0.0f && wyB == 0.0f) continue;       // wave-uniform
    if (wyA == 0.0f) { wyA = wyB; wyB = 0.0f; iA = iB; }
    bool bOK = (wyB != 0.0f);

    const uint4* rpA = lp + (size_t)((h0 + iA) * W + w0) * C8;
    const uint4* rpB = bOK ? lp + (size_t)((h0 + iA + 4) * W + w0) * C8 : rpA;

    if (bOK) {
      for (int s = 0; s < ns; s += 4) {  // 8 x 16B loads in flight
        int i0 = (s << 1) + l5;
        int i1 = i0 + 2, i2 = i0 + 4, i3 = i0 + 6;
        int c0i = min(i0, cmax), c1i = min(i1, cmax);
        int c2i = min(i2, cmax), c3i = min(i3, cmax);
        uint4 a0 = rpA[(size_t)c0i * C8];
        uint4 a1 = rpA[(size_t)c1i * C8];
        uint4 a2 = rpA[(size_t)c2i * C8];
        uint4 a3 = rpA[(size_t)c3i * C8];
        uint4 b0 = rpB[(size_t)c0i * C8];
        uint4 b1 = rpB[(size_t)c1i * C8];
        uint4 b2 = rpB[(size_t)c2i * C8];
        uint4 b3 = rpB[(size_t)c3i * C8];
        float w0f = s_wx[i0], w1f = s_wx[i1], w2f = s_wx[i2], w3f = s_wx[i3];
        FMA8(acc, a0, wyA * w0f); FMA8(acc, a1, wyA * w1f);
        FMA8(acc, a2, wyA * w2f); FMA8(acc, a3, wyA * w3f);
        FMA8(acc, b0, wyB * w0f); FMA8(acc, b1, wyB * w1f);
        FMA8(acc, b2, wyB * w2f); FMA8(acc, b3, wyB * w3f);
      }
    } else {
      for (int s = 0; s < ns; s += 4) {  // 4 x 16B loads in flight
        int i0 = (s << 1) + l5;
        int i1 = i0 + 2, i2 = i0 + 4, i3 = i0 + 6;
        int c0i = min(i0, cmax), c1i = min(i1, cmax);
        int c2i = min(i2, cmax), c3i = min(i3, cmax);
        uint4 a0 = rpA[(size_t)c0i * C8];
        uint4 a1 = rpA[(size_t)c1i * C8];
        uint4 a2 = rpA[(size_t)c2i * C8];
        uint4 a3 = rpA[(size_t)c3i * C8];
        float w0f = s_wx[i0], w1f = s_wx[i1], w2f = s_wx[i2], w3f = s_wx[i3];
        FMA8(acc, a0, wyA * w0f); FMA8(acc, a1, wyA * w1f);
        FMA8(acc, a2, wyA * w2f); FMA8(acc, a3, wyA * w3f);
      }
    }
  }

  // combine cell parities across half-waves (both halves end up with the sum)
#pragma unroll
  for (int k = 0; k < 8; k++) acc[k] += __shfl_xor(acc[k], 32, 64);

  // store partials (8 floats per lane<32, stride 9 -> conflict-free), 1 barrier
  if (l5 == 0) {
    float* slot = s_red + (size_t)(wave * 32 + l31) * 9;
#pragma unroll
    for (int k = 0; k < 8; k++) slot[k] = acc[k];
  }
  __syncthreads();

  // combine 4 waves and write: thread tid = channel c (one 4B store each;
  // same-ROI blocks are co-XCD so L2 merges the stride-196B partial lines)
  int c = tid;
  int base = (c >> 3) * 9 + (c & 7);
  float v = s_red[base] + s_red[base + 32 * 9] +
            s_red[base + 2 * 32 * 9] + s_red[base + 3 * 32 * 9];
  out[((size_t)n * C + c) * PP + pq] = v;
}

// correctness safety net for unexpected shapes / tiny workspace
__global__ void prroi_fallback(const float* __restrict__ feat,
                               const float* __restrict__ rois,
                               float* __restrict__ out, int N, int C, int H, int W) {
  int idx = blockIdx.x * blockDim.x + threadIdx.x;
  if (idx >= N * C * PP) return;
  int n = idx / (C * PP), r = idx % (C * PP);
  int c = r / PP, pq = r % PP;
  int p = pq / POOLED, q = pq % POOLED;
  float x1 = rois[n * 5 + 1] * SCALE, y1 = rois[n * 5 + 2] * SCALE;
  float x2 = rois[n * 5 + 3] * SCALE, y2 = rois[n * 5 + 4] * SCALE;
  int bi = (int)rois[n * 5 + 0];
  float bw = (x2 - x1) / POOLED, bh = (y2 - y1) / POOLED;
  float xlo = x1 + q * bw, xhi = xlo + bw;
  float ylo = y1 + p * bh, yhi = ylo + bh;
  float area = fmaxf(bw * bh, 0.0f);
  float inv_area = (area > 0.0f) ? 1.0f / fmaxf(area, 1e-12f) : 0.0f;
  const float* f = feat + ((size_t)bi * C + c) * H * W;
  float acc = 0.0f;
  int h0 = max(0, (int)floorf(ylo)), h1 = min(H - 1, (int)ceilf(yhi));
  int w0 = max(0, (int)floorf(xlo)), w1 = min(W - 1, (int)ceilf(xhi));
  for (int h = h0; h <= h1; h++) {
    float wy = hat_cdf(yhi - h) - hat_cdf(ylo - h);
    for (int w = w0; w <= w1; w++) {
      float wx = hat_cdf(xhi - w) - hat_cdf(xlo - w);
      acc += f[h * W + w] * wy * wx;
    }
  }
  out[idx] = acc * inv_area;
}

extern "C" void kernel_launch(void* const* d_in, const int* in_sizes, int n_in,
                              void* d_out, int out_size, void* d_ws, size_t ws_size,
                              hipStream_t stream) {
  const float* feat = (const float*)d_in[0];
  const float* rois = (const float*)d_in[1];
  float* out = (float*)d_out;

  const int B = 2, H = 100, W = 100, S = H * W;
  int N = in_sizes[1] / 5;
  int C = out_size / (N * PP);  // 256

  size_t need = (size_t)B * S * C * sizeof(__hip_bfloat16);
  if (C == 256 && ws_size >= need) {
    __hip_bfloat16* ft = (__hip_bfloat16*)d_ws;
    dim3 tb(32, 8);
    dim3 tg((S + 31) / 32, (C + 31) / 32, B);
    transpose_bf16_kernel<<<tg, tb, 0, stream>>>(feat, ft, C, S);
    prroi_kernel<<<N * PP, TW, 0, stream>>>(ft, rois, out, N, C, H, W);
  } else {
    int total = N * C * PP;
    prroi_fallback<<<(total + 255) / 256, 256, 0, stream>>>(feat, rois, out, N, C, H, W);
  }
}

// Round 17
// 46.948 us; speedup vs baseline: 1.1724x; 1.1724x over previous
//
#include <hip/hip_runtime.h>
#include <hip/hip_bf16.h>

#define POOLED 7
#define PP 49
#define SCALE 0.0625f
#define RMAX 20   // max rows per p-bin: bh<=14.2 -> tight support <= 17
#define QMAX 24   // max cols per q-bin (+1 for odd-ns tail index); zero-filled
#define TW 256    // 4 waves = 4 row-slots

// antiderivative of unit hat: Phi(u), Phi(-inf)=0, matches reference _hat_cdf
__device__ __forceinline__ float hat_cdf(float u) {
  if (u <= 0.0f) {
    float t = fminf(fmaxf(u + 1.0f, 0.0f), 1.0f);
    return 0.5f * t * t;
  } else {
    float t = fminf(fmaxf(1.0f - u, 0.0f), 1.0f);
    return 1.0f - 0.5f * t * t;
  }
}

__device__ __forceinline__ float bf_lo(uint32_t u) { return __uint_as_float(u << 16); }
__device__ __forceinline__ float bf_hi(uint32_t u) { return __uint_as_float(u & 0xffff0000u); }

// A[8] += unpack8(U) * WT  (params must not collide with .x/.y/.z/.w members)
#define FMA8(A, U, WT) do { \
  (A)[0] = fmaf(bf_lo((U).x), (WT), (A)[0]); (A)[1] = fmaf(bf_hi((U).x), (WT), (A)[1]); \
  (A)[2] = fmaf(bf_lo((U).y), (WT), (A)[2]); (A)[3] = fmaf(bf_hi((U).y), (WT), (A)[3]); \
  (A)[4] = fmaf(bf_lo((U).z), (WT), (A)[4]); (A)[5] = fmaf(bf_hi((U).z), (WT), (A)[5]); \
  (A)[6] = fmaf(bf_lo((U).w), (WT), (A)[6]); (A)[7] = fmaf(bf_hi((U).w), (WT), (A)[7]); \
} while (0)

// f32 [B][C][S] -> bf16 [B][S][C]  (S = H*W), coalesced both sides
__global__ __launch_bounds__(256)
void transpose_bf16_kernel(const float* __restrict__ in,
                           __hip_bfloat16* __restrict__ out, int C, int S) {
  __shared__ float tile[32][33];
  int b  = blockIdx.z;
  int s0 = blockIdx.x * 32;
  int c0 = blockIdx.y * 32;
  const float* inb = in + (size_t)b * C * S;
  __hip_bfloat16* outb = out + (size_t)b * S * C;
  int tx = threadIdx.x, ty = threadIdx.y;
#pragma unroll
  for (int j = 0; j < 4; j++) {
    int c = c0 + ty + j * 8, s = s0 + tx;
    tile[ty + j * 8][tx] = (c < C && s < S) ? inb[(size_t)c * S + s] : 0.0f;
  }
  __syncthreads();
#pragma unroll
  for (int j = 0; j < 4; j++) {
    int s = s0 + ty + j * 8, c = c0 + tx;
    if (s < S && c < C) outb[(size_t)s * C + c] = __float2bfloat16(tile[tx][ty + j * 8]);
  }
}

// One 4-wave block per (roi n, bin p, bin q) -- EXACTLY r15's structure
// (finest granule, 12544 blocks, chunked XCD swizzle, bf16 NHWC scratch,
// uint4 half-wave loads: lane l owns 8 ch ((l&31)*8), bit l>>5 picks cell
// parity; 2-sub-step unroll -- r16's 4-step padding wasted up to 4x FMAs on
// small bins and REGRESSED). r17's single change: barrier-free weight fill --
// each wave redundantly computes ALL weights (one lane-pass; QMAX=24 and
// rows<=20 both < 64) and writes identical values to LDS; within-wave
// lgkmcnt ordering covers its own reads -> one barrier per block, not two.
__global__ __launch_bounds__(TW, 4)
void prroi_kernel(const __hip_bfloat16* __restrict__ ft,
                  const float* __restrict__ rois,
                  float* __restrict__ out, int N, int C, int H, int W) {
  __shared__ float s_wx[QMAX];
  __shared__ float s_wy[RMAX];
  __shared__ float s_red[4 * 32 * 9];  // 4,608 B; stride 9 coprime w/ 32 banks

  int nb = gridDim.x;
  int bid = blockIdx.x;
  if ((nb & 7) == 0) {
    // chunked XCD swizzle: one ROI's 49 blocks stay on one XCD for L2 reuse
    int cpx = nb >> 3;
    bid = (bid & 7) * cpx + (bid >> 3);
  }
  int n = bid / PP;
  int pq = bid - n * PP;
  int p = pq / POOLED, q = pq - p * POOLED;

  int tid = threadIdx.x;
  int wave = tid >> 6, lane = tid & 63;  // wave = row-slot
  int l5 = lane >> 5;                    // cell parity this lane covers
  int l31 = lane & 31;                   // channel-octet index (8 ch)

  // uniform roi geometry (broadcast loads)
  float bif = rois[n * 5 + 0];
  float x1  = rois[n * 5 + 1] * SCALE;
  float y1  = rois[n * 5 + 2] * SCALE;
  float x2  = rois[n * 5 + 3] * SCALE;
  float y2  = rois[n * 5 + 4] * SCALE;
  int bi = (int)bif;
  float bw = (x2 - x1) * (1.0f / POOLED);
  float bh = (y2 - y1) * (1.0f / POOLED);
  float ylo = y1 + p * bh, yhi = ylo + bh;
  float xlo = x1 + q * bw, xhi = xlo + bw;

  // tight supports (next cell out has exactly-zero hat weight)
  int h0 = max(0, (int)floorf(ylo));
  int h1 = min(H - 1, (int)ceilf(yhi));
  int rows = h1 - h0 + 1;
  if (rows > RMAX) rows = RMAX;      // cannot trigger here; safety only
  int w0 = max(0, (int)floorf(xlo));
  int w1 = min(W - 1, (int)ceilf(xhi));
  int nw = w1 - w0 + 1;
  if (nw > QMAX - 1) nw = QMAX - 1;  // cannot trigger here; safety only

  float area = fmaxf(bw * bh, 0.0f);
  float inv_area = (area > 0.0f) ? 1.0f / fmaxf(area, 1e-12f) : 0.0f;

  // per-wave redundant weight fill: every wave writes identical values, so no
  // cross-wave barrier is needed (within-wave lgkmcnt orders write->read).
  {
    int i = lane;
    if (i < QMAX) {
      float v = 0.0f;
      if (i < nw) {
        float j = (float)(w0 + i);
        v = (hat_cdf(xhi - j) - hat_cdf(xlo - j)) * inv_area;
      }
      s_wx[i] = v;
    }
    if (i < rows) {
      float j = (float)(h0 + i);
      s_wy[i] = hat_cdf(yhi - j) - hat_cdf(ylo - j);
    }
  }

  float acc[8];
#pragma unroll
  for (int k = 0; k < 8; k++) acc[k] = 0.0f;

  const int C8 = C >> 3;  // uint4 (=8ch) per cell
  const uint4* lp = (const uint4*)ft + ((size_t)bi * H * W) * C8 + l31;
  const int ns = (nw + 1) >> 1;  // cell-pair steps (block-uniform)
  const int cmax = nw - 1;       // address clamp (weight exactly 0 beyond)

  // rows round-robin over 4 row-slots; fuse pairs (ih, ih+4); 2-step unroll
  for (int ih = wave; ih < rows; ih += 8) {
    int iA = ih, iB = ih + 4;
    float wyA = s_wy[iA];
    float wyB = (iB < rows) ? s_wy[iB] : 0.0f;
    if (wyA == 0.0f && wyB == 0.0f) continue;       // wave-uniform
    if (wyA == 0.0f) { wyA = wyB; wyB = 0.0f; iA = iB; }
    bool bOK = (wyB != 0.0f);

    const uint4* rpA = lp + (size_t)((h0 + iA) * W + w0) * C8;
    const uint4* rpB = bOK ? lp + (size_t)((h0 + iA + 4) * W + w0) * C8 : rpA;

    int s = 0;
    if (bOK) {
      for (; s + 1 < ns; s += 2) {  // 4 x 16B loads in flight (8 cells of data)
        int i0 = (s << 1) + l5;
        int i1 = i0 + 2;
        int c0i = min(i0, cmax), c1i = min(i1, cmax);
        uint4 uA0 = rpA[(size_t)c0i * C8];
        uint4 uA1 = rpA[(size_t)c1i * C8];
        uint4 uB0 = rpB[(size_t)c0i * C8];
        uint4 uB1 = rpB[(size_t)c1i * C8];
        float wf0 = s_wx[i0], wf1 = s_wx[i1];
        FMA8(acc, uA0, wyA * wf0); FMA8(acc, uA1, wyA * wf1);
        FMA8(acc, uB0, wyB * wf0); FMA8(acc, uB1, wyB * wf1);
      }
      if (s < ns) {
        int i0 = (s << 1) + l5;
        int c0i = min(i0, cmax);
        uint4 uA = rpA[(size_t)c0i * C8];
        uint4 uB = rpB[(size_t)c0i * C8];
        float wf0 = s_wx[i0];
        FMA8(acc, uA, wyA * wf0);
        FMA8(acc, uB, wyB * wf0);
      }
    } else {
      for (; s + 1 < ns; s += 2) {
        int i0 = (s << 1) + l5;
        int i1 = i0 + 2;
        int c0i = min(i0, cmax), c1i = min(i1, cmax);
        uint4 uA0 = rpA[(size_t)c0i * C8];
        uint4 uA1 = rpA[(size_t)c1i * C8];
        float wf0 = s_wx[i0], wf1 = s_wx[i1];
        FMA8(acc, uA0, wyA * wf0); FMA8(acc, uA1, wyA * wf1);
      }
      if (s < ns) {
        int i0 = (s << 1) + l5;
        int c0i = min(i0, cmax);
        uint4 uA = rpA[(size_t)c0i * C8];
        float wf0 = s_wx[i0];
        FMA8(acc, uA, wyA * wf0);
      }
    }
  }

  // combine cell parities across half-waves (both halves end up with the sum)
#pragma unroll
  for (int k = 0; k < 8; k++) acc[k] += __shfl_xor(acc[k], 32, 64);

  // store partials (8 floats per lane<32, stride 9 -> conflict-free), 1 barrier
  if (l5 == 0) {
    float* slot = s_red + (size_t)(wave * 32 + l31) * 9;
#pragma unroll
    for (int k = 0; k < 8; k++) slot[k] = acc[k];
  }
  __syncthreads();

  // combine 4 waves and write: thread tid = channel c (one 4B store each;
  // same-ROI blocks are co-XCD so L2 merges the stride-196B partial lines)
  int c = tid;
  int base = (c >> 3) * 9 + (c & 7);
  float v = s_red[base] + s_red[base + 32 * 9] +
            s_red[base + 2 * 32 * 9] + s_red[base + 3 * 32 * 9];
  out[((size_t)n * C + c) * PP + pq] = v;
}

// correctness safety net for unexpected shapes / tiny workspace
__global__ void prroi_fallback(const float* __restrict__ feat,
                               const float* __restrict__ rois,
                               float* __restrict__ out, int N, int C, int H, int W) {
  int idx = blockIdx.x * blockDim.x + threadIdx.x;
  if (idx >= N * C * PP) return;
  int n = idx / (C * PP), r = idx % (C * PP);
  int c = r / PP, pq = r % PP;
  int p = pq / POOLED, q = pq % POOLED;
  float x1 = rois[n * 5 + 1] * SCALE, y1 = rois[n * 5 + 2] * SCALE;
  float x2 = rois[n * 5 + 3] * SCALE, y2 = rois[n * 5 + 4] * SCALE;
  int bi = (int)rois[n * 5 + 0];
  float bw = (x2 - x1) / POOLED, bh = (y2 - y1) / POOLED;
  float xlo = x1 + q * bw, xhi = xlo + bw;
  float ylo = y1 + p * bh, yhi = ylo + bh;
  float area = fmaxf(bw * bh, 0.0f);
  float inv_area = (area > 0.0f) ? 1.0f / fmaxf(area, 1e-12f) : 0.0f;
  const float* f = feat + ((size_t)bi * C + c) * H * W;
  float acc = 0.0f;
  int h0 = max(0, (int)floorf(ylo)), h1 = min(H - 1, (int)ceilf(yhi));
  int w0 = max(0, (int)floorf(xlo)), w1 = min(W - 1, (int)ceilf(xhi));
  for (int h = h0; h <= h1; h++) {
    float wy = hat_cdf(yhi - h) - hat_cdf(ylo - h);
    for (int w = w0; w <= w1; w++) {
      float wx = hat_cdf(xhi - w) - hat_cdf(xlo - w);
      acc += f[h * W + w] * wy * wx;
    }
  }
  out[idx] = acc * inv_area;
}

extern "C" void kernel_launch(void* const* d_in, const int* in_sizes, int n_in,
                              void* d_out, int out_size, void* d_ws, size_t ws_size,
                              hipStream_t stream) {
  const float* feat = (const float*)d_in[0];
  const float* rois = (const float*)d_in[1];
  float* out = (float*)d_out;

  const int B = 2, H = 100, W = 100, S = H * W;
  int N = in_sizes[1] / 5;
  int C = out_size / (N * PP);  // 256

  size_t need = (size_t)B * S * C * sizeof(__hip_bfloat16);
  if (C == 256 && ws_size >= need) {
    __hip_bfloat16* ft = (__hip_bfloat16*)d_ws;
    dim3 tb(32, 8);
    dim3 tg((S + 31) / 32, (C + 31) / 32, B);
    transpose_bf16_kernel<<<tg, tb, 0, stream>>>(feat, ft, C, S);
    prroi_kernel<<<N * PP, TW, 0, stream>>>(ft, rois, out, N, C, H, W);
  } else {
    int total = N * C * PP;
    prroi_fallback<<<(total + 255) / 256, 256, 0, stream>>>(feat, rois, out, N, C, H, W);
  }
}